// Round 1
// baseline (218.177 us; speedup 1.0000x reference)
//
#include <hip/hip_runtime.h>
#include <math.h>

// PoseDisentangler: bone_len + bone_dir from (B,N,17,3) f32 poses.
// One thread per bone. parent[j] packed as nibbles in a 64-bit constant.
// Memory-bound: 107 MB read + 134 MB write -> ~38 us roofline at 6.3 TB/s.

#define NJOINT 17
#define NBONE  16
// nibble j = H36M_PARENT[j] = {0,1,2,0,4,5,0,7,8,9,8,11,12,8,14,15}
#define PARENT_PACK 0xFE8CB89870540210ull

__global__ __launch_bounds__(256) void pose_bones_kernel(
    const float* __restrict__ in,   // (P, 17, 3) flat, P = B*N
    float* __restrict__ out_len,    // (P, 16)
    float* __restrict__ out_dir,    // (P, 16, 3)
    unsigned int total)             // P * 16
{
    unsigned int gid = blockIdx.x * 256u + threadIdx.x;
    if (gid >= total) return;

    const unsigned int j    = gid & 15u;        // bone index
    const unsigned int pose = gid >> 4;
    const unsigned int base = pose * (NJOINT * 3u);

    const unsigned int parent = (unsigned int)((PARENT_PACK >> (4u * j)) & 15ull);

    const unsigned int coff = base + (j + 1u) * 3u;
    const unsigned int poff = base + parent * 3u;

    const float cx = in[coff + 0u];
    const float cy = in[coff + 1u];
    const float cz = in[coff + 2u];
    const float px = in[poff + 0u];
    const float py = in[poff + 1u];
    const float pz = in[poff + 2u];

    const float vx = cx - px;
    const float vy = cy - py;
    const float vz = cz - pz;

    const float len = sqrtf(vx * vx + vy * vy + vz * vz);
    const float l   = fmaxf(len, 1e-12f);

    out_len[gid] = len;
    const unsigned int doff = gid * 3u;
    out_dir[doff + 0u] = vx / l;
    out_dir[doff + 1u] = vy / l;
    out_dir[doff + 2u] = vz / l;
}

extern "C" void kernel_launch(void* const* d_in, const int* in_sizes, int n_in,
                              void* d_out, int out_size, void* d_ws, size_t ws_size,
                              hipStream_t stream) {
    const float* in = (const float*)d_in[0];
    float* out = (float*)d_out;

    // in_sizes[0] = P * 17 * 3
    const unsigned int poses = (unsigned int)(in_sizes[0] / (NJOINT * 3));
    const unsigned int total = poses * NBONE;          // bones = len elements
    float* out_len = out;                              // first P*16 floats
    float* out_dir = out + (size_t)total;              // next  P*16*3 floats

    const unsigned int blocks = (total + 255u) / 256u;
    pose_bones_kernel<<<blocks, 256, 0, stream>>>(in, out_len, out_dir, total);
}

// Round 2
// 211.384 us; speedup vs baseline: 1.0321x; 1.0321x over previous
//
#include <hip/hip_runtime.h>
#include <math.h>

// PoseDisentangler: bone_len + bone_dir from (B,N,17,3) f32 poses.
// Memory-bound: 107 MB read + 134 MB write -> ~38 us roofline at 6.3 TB/s.
//
// R1: LDS-staged fully-vectorized version. 256-thread block handles 64 poses:
//   - global float4 loads (64*51 floats = 816 float4) -> LDS
//   - each thread computes 4 bones, writes len as one float4 (coalesced),
//     stages dir (12 floats, 16B-aligned) into LDS
//   - dir written back as coalesced float4 (768 per block)

#define NJOINT 17
#define NBONE  16
// nibble j = H36M_PARENT[j] = {0,1,2,0,4,5,0,7,8,9,8,11,12,8,14,15}
#define PARENT_PACK 0xFE8CB89870540210ull

#define PPB 64                     // poses per block
#define IN_FLOATS  (PPB * NJOINT * 3)   // 3264 (= 816 float4)
#define DIR_FLOATS (PPB * NBONE * 3)    // 3072 (= 768 float4)
#define LEN_FLOATS (PPB * NBONE)        // 1024 (= 256 float4)

__global__ __launch_bounds__(256) void pose_bones_kernel(
    const float* __restrict__ in,   // (P, 17, 3)
    float* __restrict__ out_len,    // (P, 16)
    float* __restrict__ out_dir,    // (P, 16, 3)
    unsigned int P)                 // number of poses
{
    __shared__ float s_in[IN_FLOATS];
    __shared__ float s_dir[DIR_FLOATS];

    const unsigned int tid   = threadIdx.x;
    const unsigned int block = blockIdx.x;
    const unsigned int pose0 = block * PPB;

    if (pose0 + PPB <= P) {
        // ---- fast path: full block of 64 poses ----
        // stage input: 816 float4, 256 threads -> 3 full rounds + 48 extras
        const float4* gin  = (const float4*)(in + (size_t)pose0 * (NJOINT * 3));
        float4*       sin4 = (float4*)s_in;
        sin4[tid]       = gin[tid];
        sin4[tid + 256] = gin[tid + 256];
        sin4[tid + 512] = gin[tid + 512];
        if (tid < IN_FLOATS / 4 - 768) sin4[tid + 768] = gin[tid + 768];
        __syncthreads();

        // compute: thread t -> pose (t>>2), bones (t&3)*4 .. +3
        // global bone-in-block index bb = 4*t + i  (contiguous per thread)
        const unsigned int p  = tid >> 2;
        const unsigned int j0 = (tid & 3u) * 4u;
        const float* pp = s_in + p * (NJOINT * 3);

        float lenv[4];
        float dirv[12];
        #pragma unroll
        for (int i = 0; i < 4; ++i) {
            const unsigned int j = j0 + (unsigned int)i;
            const unsigned int parent = (unsigned int)((PARENT_PACK >> (4u * j)) & 15ull);
            const float vx = pp[(j + 1u) * 3u + 0u] - pp[parent * 3u + 0u];
            const float vy = pp[(j + 1u) * 3u + 1u] - pp[parent * 3u + 1u];
            const float vz = pp[(j + 1u) * 3u + 2u] - pp[parent * 3u + 2u];
            const float len = sqrtf(vx * vx + vy * vy + vz * vz);
            const float l   = fmaxf(len, 1e-12f);
            lenv[i] = len;
            dirv[i * 3 + 0] = vx / l;
            dirv[i * 3 + 1] = vy / l;
            dirv[i * 3 + 2] = vz / l;
        }

        // len: thread t owns out_len[pose0*16 + 4t .. 4t+3] -> one float4
        ((float4*)(out_len + (size_t)pose0 * NBONE))[tid] =
            make_float4(lenv[0], lenv[1], lenv[2], lenv[3]);

        // stage dir: 12 consecutive floats at s_dir + 12*t (48B, 16B-aligned)
        float4* sd4 = (float4*)(s_dir + tid * 12u);
        sd4[0] = make_float4(dirv[0], dirv[1], dirv[2],  dirv[3]);
        sd4[1] = make_float4(dirv[4], dirv[5], dirv[6],  dirv[7]);
        sd4[2] = make_float4(dirv[8], dirv[9], dirv[10], dirv[11]);
        __syncthreads();

        // dir writeback: 768 float4, coalesced
        float4*       gdir = (float4*)(out_dir + (size_t)pose0 * (NBONE * 3));
        const float4* sd   = (const float4*)s_dir;
        gdir[tid]       = sd[tid];
        gdir[tid + 256] = sd[tid + 256];
        gdir[tid + 512] = sd[tid + 512];
    } else {
        // ---- tail path: bounds-checked scalar (not hit when P % 64 == 0) ----
        const unsigned int total = P * NBONE;
        for (unsigned int gid = pose0 * NBONE + tid; gid < total; gid += 256u) {
            const unsigned int j    = gid & 15u;
            const unsigned int pose = gid >> 4;
            const unsigned int base = pose * (NJOINT * 3u);
            const unsigned int parent = (unsigned int)((PARENT_PACK >> (4u * j)) & 15ull);
            const unsigned int coff = base + (j + 1u) * 3u;
            const unsigned int poff = base + parent * 3u;
            const float vx = in[coff + 0u] - in[poff + 0u];
            const float vy = in[coff + 1u] - in[poff + 1u];
            const float vz = in[coff + 2u] - in[poff + 2u];
            const float len = sqrtf(vx * vx + vy * vy + vz * vz);
            const float l   = fmaxf(len, 1e-12f);
            out_len[gid] = len;
            out_dir[gid * 3u + 0u] = vx / l;
            out_dir[gid * 3u + 1u] = vy / l;
            out_dir[gid * 3u + 2u] = vz / l;
        }
    }
}

extern "C" void kernel_launch(void* const* d_in, const int* in_sizes, int n_in,
                              void* d_out, int out_size, void* d_ws, size_t ws_size,
                              hipStream_t stream) {
    const float* in = (const float*)d_in[0];
    float* out = (float*)d_out;

    const unsigned int P = (unsigned int)(in_sizes[0] / (NJOINT * 3));
    float* out_len = out;                       // first P*16 floats
    float* out_dir = out + (size_t)P * NBONE;   // next  P*16*3 floats

    const unsigned int blocks = (P + PPB - 1u) / PPB;
    pose_bones_kernel<<<blocks, 256, 0, stream>>>(in, out_len, out_dir, P);
}

// Round 4
// 201.479 us; speedup vs baseline: 1.0829x; 1.0492x over previous
//
#include <hip/hip_runtime.h>
#include <math.h>

// PoseDisentangler: bone_len + bone_dir from (B,N,17,3) f32 poses.
// Memory-bound: 107 MB read + 134 MB write -> ~36 us floor at 6.7 TB/s.
//
// R3: R1 LDS-staged vectorized structure + non-temporal loads/stores.
// Uses clang ext_vector_type(4) float (native vector) because
// __builtin_nontemporal_* rejects HIP_vector_type float4.

#define NJOINT 17
#define NBONE  16
// nibble j = H36M_PARENT[j] = {0,1,2,0,4,5,0,7,8,9,8,11,12,8,14,15}
#define PARENT_PACK 0xFE8CB89870540210ull

#define PPB 64                          // poses per block
#define IN_FLOATS  (PPB * NJOINT * 3)   // 3264 (= 816 vec4)
#define DIR_FLOATS (PPB * NBONE * 3)    // 3072 (= 768 vec4)

typedef float vf4 __attribute__((ext_vector_type(4)));

__global__ __launch_bounds__(256) void pose_bones_kernel(
    const float* __restrict__ in,   // (P, 17, 3)
    float* __restrict__ out_len,    // (P, 16)
    float* __restrict__ out_dir,    // (P, 16, 3)
    unsigned int P)                 // number of poses
{
    __shared__ float s_in[IN_FLOATS];
    __shared__ float s_dir[DIR_FLOATS];

    const unsigned int tid   = threadIdx.x;
    const unsigned int block = blockIdx.x;
    const unsigned int pose0 = block * PPB;

    if (pose0 + PPB <= P) {
        // ---- fast path: full block of 64 poses ----
        const vf4* gin  = (const vf4*)(in + (size_t)pose0 * (NJOINT * 3));
        vf4*       sin4 = (vf4*)s_in;
        sin4[tid]       = __builtin_nontemporal_load(gin + tid);
        sin4[tid + 256] = __builtin_nontemporal_load(gin + tid + 256);
        sin4[tid + 512] = __builtin_nontemporal_load(gin + tid + 512);
        if (tid < IN_FLOATS / 4 - 768)
            sin4[tid + 768] = __builtin_nontemporal_load(gin + tid + 768);
        __syncthreads();

        // compute: thread t -> pose (t>>2), bones (t&3)*4 .. +3
        const unsigned int p  = tid >> 2;
        const unsigned int j0 = (tid & 3u) * 4u;
        const float* pp = s_in + p * (NJOINT * 3);

        float lenv[4];
        float dirv[12];
        #pragma unroll
        for (int i = 0; i < 4; ++i) {
            const unsigned int j = j0 + (unsigned int)i;
            const unsigned int parent = (unsigned int)((PARENT_PACK >> (4u * j)) & 15ull);
            const float vx = pp[(j + 1u) * 3u + 0u] - pp[parent * 3u + 0u];
            const float vy = pp[(j + 1u) * 3u + 1u] - pp[parent * 3u + 1u];
            const float vz = pp[(j + 1u) * 3u + 2u] - pp[parent * 3u + 2u];
            const float len = sqrtf(vx * vx + vy * vy + vz * vz);
            const float l   = fmaxf(len, 1e-12f);
            lenv[i] = len;
            dirv[i * 3 + 0] = vx / l;
            dirv[i * 3 + 1] = vy / l;
            dirv[i * 3 + 2] = vz / l;
        }

        // len: thread t owns out_len[pose0*16 + 4t .. 4t+3] -> one vec4 (nt)
        {
            vf4 lv = { lenv[0], lenv[1], lenv[2], lenv[3] };
            __builtin_nontemporal_store(
                lv, (vf4*)(out_len + (size_t)pose0 * NBONE) + tid);
        }

        // stage dir: 12 consecutive floats at s_dir + 12*t (48B, 16B-aligned)
        vf4* sd4 = (vf4*)(s_dir + tid * 12u);
        sd4[0] = (vf4){ dirv[0], dirv[1], dirv[2],  dirv[3]  };
        sd4[1] = (vf4){ dirv[4], dirv[5], dirv[6],  dirv[7]  };
        sd4[2] = (vf4){ dirv[8], dirv[9], dirv[10], dirv[11] };
        __syncthreads();

        // dir writeback: 768 vec4, coalesced, non-temporal
        vf4*       gdir = (vf4*)(out_dir + (size_t)pose0 * (NBONE * 3));
        const vf4* sd   = (const vf4*)s_dir;
        __builtin_nontemporal_store(sd[tid],       gdir + tid);
        __builtin_nontemporal_store(sd[tid + 256], gdir + tid + 256);
        __builtin_nontemporal_store(sd[tid + 512], gdir + tid + 512);
    } else {
        // ---- tail path: bounds-checked scalar (not hit when P % 64 == 0) ----
        const unsigned int total = P * NBONE;
        for (unsigned int gid = pose0 * NBONE + tid; gid < total; gid += 256u) {
            const unsigned int j    = gid & 15u;
            const unsigned int pose = gid >> 4;
            const unsigned int base = pose * (NJOINT * 3u);
            const unsigned int parent = (unsigned int)((PARENT_PACK >> (4u * j)) & 15ull);
            const unsigned int coff = base + (j + 1u) * 3u;
            const unsigned int poff = base + parent * 3u;
            const float vx = in[coff + 0u] - in[poff + 0u];
            const float vy = in[coff + 1u] - in[poff + 1u];
            const float vz = in[coff + 2u] - in[poff + 2u];
            const float len = sqrtf(vx * vx + vy * vy + vz * vz);
            const float l   = fmaxf(len, 1e-12f);
            out_len[gid] = len;
            out_dir[gid * 3u + 0u] = vx / l;
            out_dir[gid * 3u + 1u] = vy / l;
            out_dir[gid * 3u + 2u] = vz / l;
        }
    }
}

extern "C" void kernel_launch(void* const* d_in, const int* in_sizes, int n_in,
                              void* d_out, int out_size, void* d_ws, size_t ws_size,
                              hipStream_t stream) {
    const float* in = (const float*)d_in[0];
    float* out = (float*)d_out;

    const unsigned int P = (unsigned int)(in_sizes[0] / (NJOINT * 3));
    float* out_len = out;                       // first P*16 floats
    float* out_dir = out + (size_t)P * NBONE;   // next  P*16*3 floats

    const unsigned int blocks = (P + PPB - 1u) / PPB;
    pose_bones_kernel<<<blocks, 256, 0, stream>>>(in, out_len, out_dir, P);
}